// Round 1
// baseline (219.426 us; speedup 1.0000x reference)
//
#include <hip/hip_runtime.h>
#include <math.h>

#define TPB 256
#define EPT 16      // elements per thread
#define NN  4096    // row length (fixed by problem)
#define KSEL 410    // K = round(4096 * 0.1)

// Monotonic float->uint key: larger float => larger unsigned key.
__device__ __forceinline__ unsigned sortkey(float f) {
    unsigned u = __float_as_uint(f);
    return u ^ ((u & 0x80000000u) ? 0xFFFFFFFFu : 0x80000000u);
}

template <bool USE_WS>
__global__ __launch_bounds__(TPB)
void skw_main(const float* __restrict__ x, const float* __restrict__ g,
              float* __restrict__ out, float* __restrict__ rowH,
              float* __restrict__ entAcc, float invB)
{
    const int row = blockIdx.x;
    const int t = threadIdx.x;
    const size_t base = (size_t)row * NN + (size_t)t * EPT;

    float xv[EPT];
    unsigned key[EPT];

    // ---- load x, gumbel; build sort keys with IEEE-exact s = x/10 + g ----
    const float4* xp = reinterpret_cast<const float4*>(x + base);
    const float4* gp = reinterpret_cast<const float4*>(g + base);
#pragma unroll
    for (int q = 0; q < EPT / 4; ++q) {
        float4 xx = xp[q];
        float4 gg = gp[q];
        xv[4*q+0] = xx.x; xv[4*q+1] = xx.y; xv[4*q+2] = xx.z; xv[4*q+3] = xx.w;
        key[4*q+0] = sortkey(xx.x / 10.0f + gg.x);
        key[4*q+1] = sortkey(xx.y / 10.0f + gg.y);
        key[4*q+2] = sortkey(xx.z / 10.0f + gg.z);
        key[4*q+3] = sortkey(xx.w / 10.0f + gg.w);
    }

    __shared__ unsigned hist[256];
    __shared__ float red[256];
    __shared__ unsigned sh_digit, sh_above;

    // ---- entropy of softmax(x/10) for this row ----
    float lm = -INFINITY;
#pragma unroll
    for (int j = 0; j < EPT; ++j) lm = fmaxf(lm, xv[j] * 0.1f);
    red[t] = lm; __syncthreads();
    for (int s = 128; s > 0; s >>= 1) { if (t < s) red[t] = fmaxf(red[t], red[t + s]); __syncthreads(); }
    const float m = red[0];
    __syncthreads();

    float sZ = 0.f, sZL = 0.f;
#pragma unroll
    for (int j = 0; j < EPT; ++j) {
        float d = xv[j] * 0.1f - m;
        float e = __expf(d);
        sZ += e; sZL += e * d;
    }
    red[t] = sZ; __syncthreads();
    for (int s = 128; s > 0; s >>= 1) { if (t < s) red[t] += red[t + s]; __syncthreads(); }
    const float Z = red[0];
    __syncthreads();
    red[t] = sZL; __syncthreads();
    for (int s = 128; s > 0; s >>= 1) { if (t < s) red[t] += red[t + s]; __syncthreads(); }
    if (t == 0) {
        float H = __logf(Z) - red[0] / Z;   // H = lnZ - E[l-m]
        if (USE_WS) rowH[row] = H;
        else atomicAdd(entAcc, H * invB);
    }

    // ---- radix select: exact K-th largest key (MSB-first, 4x8-bit) ----
    unsigned prefix = 0;
    unsigned Kr = KSEL;
#pragma unroll
    for (int p = 0; p < 4; ++p) {
        const int shift = 24 - 8 * p;
        hist[t] = 0;
        __syncthreads();
#pragma unroll
        for (int j = 0; j < EPT; ++j) {
            unsigned k = key[j];
            bool cand;
            if (p == 0) cand = true;
            else        cand = ((k >> (shift + 8)) == prefix);
            if (cand) atomicAdd(&hist[(k >> shift) & 255u], 1u);
        }
        __syncthreads();
        // inclusive suffix scan: hist[b] = # candidates with digit >= b
        for (int s = 1; s < 256; s <<= 1) {
            unsigned v = hist[t];
            unsigned o = (t + s < 256) ? hist[t + s] : 0u;
            __syncthreads();
            hist[t] = v + o;
            __syncthreads();
        }
        unsigned cum = hist[t];
        unsigned cumNext = (t < 255) ? hist[t + 1] : 0u;
        if (cum >= Kr && cumNext < Kr) { sh_digit = (unsigned)t; sh_above = cumNext; }
        __syncthreads();
        prefix = (prefix << 8) | sh_digit;
        Kr -= sh_above;           // remaining slots among keys with this digit
        __syncthreads();
    }
    const unsigned thr = prefix;  // exact K-th largest key; Kr = # equals to take

    // ---- lowest-index-first tie selection: exclusive scan of equal counts ----
    unsigned eq = 0;
#pragma unroll
    for (int j = 0; j < EPT; ++j) eq += (key[j] == thr) ? 1u : 0u;
    hist[t] = eq;
    __syncthreads();
    for (int s = 1; s < 256; s <<= 1) {
        unsigned v = hist[t];
        unsigned o = (t >= s) ? hist[t - s] : 0u;
        __syncthreads();
        hist[t] = v + o;
        __syncthreads();
    }
    unsigned pos = hist[t] - eq;  // exclusive prefix of equals before my chunk

    // ---- write out = x * mask ----
    float4* op = reinterpret_cast<float4*>(out + base);
#pragma unroll
    for (int q = 0; q < EPT / 4; ++q) {
        float vals[4];
#pragma unroll
        for (int jj = 0; jj < 4; ++jj) {
            int j = 4 * q + jj;
            bool sel;
            if (key[j] > thr)       sel = true;
            else if (key[j] == thr) { sel = (pos < Kr); ++pos; }
            else                    sel = false;
            vals[jj] = sel ? xv[j] : 0.0f;
        }
        float4 o4; o4.x = vals[0]; o4.y = vals[1]; o4.z = vals[2]; o4.w = vals[3];
        op[q] = o4;
    }
}

__global__ void skw_zero(float* p) { *p = 0.0f; }

// Deterministic fixed-order mean of rowH -> out scalar.
__global__ void skw_reduce(const float* __restrict__ rowH, float* __restrict__ outp, int B)
{
    __shared__ float red[256];
    int t = threadIdx.x;
    float s = 0.f;
    for (int i = t; i < B; i += 256) s += rowH[i];
    red[t] = s; __syncthreads();
    for (int st = 128; st > 0; st >>= 1) { if (t < st) red[t] += red[t + st]; __syncthreads(); }
    if (t == 0) *outp = red[0] / (float)B;
}

extern "C" void kernel_launch(void* const* d_in, const int* in_sizes, int n_in,
                              void* d_out, int out_size, void* d_ws, size_t ws_size,
                              hipStream_t stream)
{
    const float* x = (const float*)d_in[0];
    const float* g = (const float*)d_in[1];
    float* out = (float*)d_out;
    const int BN = in_sizes[0];
    const int B  = BN / NN;
    float* entp = out + (size_t)BN;

    if (ws_size >= (size_t)B * sizeof(float)) {
        float* rowH = (float*)d_ws;
        skw_main<true><<<B, TPB, 0, stream>>>(x, g, out, rowH, nullptr, 0.f);
        skw_reduce<<<1, 256, 0, stream>>>(rowH, entp, B);
    } else {
        // fallback if workspace is too small: atomic accumulation
        skw_zero<<<1, 1, 0, stream>>>(entp);
        skw_main<false><<<B, TPB, 0, stream>>>(x, g, out, nullptr, entp, 1.0f / (float)B);
    }
}

// Round 2
// 197.695 us; speedup vs baseline: 1.1099x; 1.1099x over previous
//
#include <hip/hip_runtime.h>
#include <math.h>

#define TPB 256
#define EPT 16      // elements per thread
#define NN  4096    // row length (fixed by problem)
#define KSEL 410    // K = round(4096 * 0.1)

// Monotonic float->uint key: larger float => larger unsigned key.
__device__ __forceinline__ unsigned sortkey(float f) {
    unsigned u = __float_as_uint(f);
    unsigned m = (unsigned)(((int)u) >> 31);     // 0x00000000 or 0xFFFFFFFF
    return u ^ (m | 0x80000000u);
}

template <bool USE_WS>
__global__ __launch_bounds__(TPB)
void skw_main(const float* __restrict__ x, const float* __restrict__ g,
              float* __restrict__ out, float* __restrict__ rowH,
              float* __restrict__ entAcc, float invB)
{
    const int row  = blockIdx.x;
    const int t    = threadIdx.x;
    const int w    = t >> 6;          // wave id 0..3
    const int lane = t & 63;
    const size_t base = (size_t)row * NN + (size_t)t * EPT;

    float xv[EPT];
    unsigned key[EPT];

    // ---- load x, gumbel; build sort keys with IEEE-exact s = x/10 + g ----
    const float4* xp = reinterpret_cast<const float4*>(x + base);
    const float4* gp = reinterpret_cast<const float4*>(g + base);
#pragma unroll
    for (int q = 0; q < EPT / 4; ++q) {
        float4 xx = xp[q];
        float4 gg = gp[q];
        xv[4*q+0] = xx.x; xv[4*q+1] = xx.y; xv[4*q+2] = xx.z; xv[4*q+3] = xx.w;
        key[4*q+0] = sortkey(xx.x / 10.0f + gg.x);
        key[4*q+1] = sortkey(xx.y / 10.0f + gg.y);
        key[4*q+2] = sortkey(xx.z / 10.0f + gg.z);
        key[4*q+3] = sortkey(xx.w / 10.0f + gg.w);
    }

    __shared__ unsigned hist4[4][256];   // per-wave histograms (no inter-wave contention)
    __shared__ unsigned wtot[4];
    __shared__ float    fred[8];
    __shared__ unsigned sh_digit, sh_above;

    // ================= entropy of softmax(x/10) =================
    float lm = -INFINITY;
#pragma unroll
    for (int j = 0; j < EPT; ++j) lm = fmaxf(lm, xv[j] * 0.1f);
#pragma unroll
    for (int s = 32; s >= 1; s >>= 1) lm = fmaxf(lm, __shfl_xor(lm, s));
    if (lane == 0) fred[w] = lm;
    __syncthreads();
    const float m = fmaxf(fmaxf(fred[0], fred[1]), fmaxf(fred[2], fred[3]));

    float sZ = 0.f, sZL = 0.f;
#pragma unroll
    for (int j = 0; j < EPT; ++j) {
        float d = xv[j] * 0.1f - m;
        float e = __expf(d);
        sZ += e; sZL += e * d;
    }
#pragma unroll
    for (int s = 32; s >= 1; s >>= 1) { sZ += __shfl_xor(sZ, s); sZL += __shfl_xor(sZL, s); }
    __syncthreads();                    // everyone done reading fred[0..3]
    if (lane == 0) { fred[w] = sZ; fred[4 + w] = sZL; }
    __syncthreads();
    if (t == 0) {
        float Z = fred[0] + fred[1] + fred[2] + fred[3];
        float L = fred[4] + fred[5] + fred[6] + fred[7];
        float H = __logf(Z) - L / Z;    // H = lnZ - E[l-m]
        if (USE_WS) rowH[row] = H;
        else atomicAdd(entAcc, H * invB);
    }

    // ======= radix select: exact K-th largest key (MSB-first, 4x8-bit) =======
    unsigned* hflat = &hist4[0][0];
    unsigned prefix = 0;
    unsigned Kr = KSEL;
#pragma unroll
    for (int p = 0; p < 4; ++p) {
        const int shift = 24 - 8 * p;
        hflat[t] = 0; hflat[t + 256] = 0; hflat[t + 512] = 0; hflat[t + 768] = 0;
        __syncthreads();
#pragma unroll
        for (int j = 0; j < EPT; ++j) {
            unsigned k = key[j];
            if (p == 0) {
                atomicAdd(&hist4[w][k >> 24], 1u);
            } else {
                if ((k >> (shift + 8)) == prefix)
                    atomicAdd(&hist4[w][(k >> shift) & 255u], 1u);
            }
        }
        __syncthreads();
        // merged bin count for bin b == t
        unsigned v = hist4[0][t] + hist4[1][t] + hist4[2][t] + hist4[3][t];
        // inclusive SUFFIX scan within wave (64 bins per wave) via shfl
#pragma unroll
        for (int s = 1; s < 64; s <<= 1) {
            unsigned tmp = __shfl(v, lane + s);
            v += (lane + s < 64) ? tmp : 0u;
        }
        if (lane == 0) wtot[w] = v;            // this wave-chunk's total
        unsigned vnext = __shfl(v, lane + 1);  // suffix starting one bin later
        __syncthreads();
        unsigned hi = 0;
#pragma unroll
        for (int c = 0; c < 4; ++c) hi += (c > w) ? wtot[c] : 0u;
        unsigned cum     = v + hi;                              // # keys with digit >= t
        unsigned cumNext = ((lane < 63) ? vnext : 0u) + hi;     // # keys with digit >  t
        if (cum >= Kr && cumNext < Kr) { sh_digit = (unsigned)t; sh_above = cumNext; }
        __syncthreads();
        prefix = (prefix << 8) | sh_digit;
        Kr -= sh_above;     // remaining slots among keys equal at this digit
    }
    const unsigned thr = prefix;   // exact K-th largest key; Kr = # equals to take

    // ===== lowest-index-first tie selection: exclusive prefix of equal counts =====
    unsigned eq = 0;
#pragma unroll
    for (int j = 0; j < EPT; ++j) eq += (key[j] == thr) ? 1u : 0u;
    unsigned v = eq;
#pragma unroll
    for (int s = 1; s < 64; s <<= 1) {          // inclusive PREFIX scan within wave
        unsigned tmp = __shfl(v, lane - s);
        v += (lane >= s) ? tmp : 0u;
    }
    if (lane == 63) wtot[w] = v;                // wave total
    __syncthreads();
    unsigned offset = 0;
#pragma unroll
    for (int c = 0; c < 4; ++c) offset += (c < w) ? wtot[c] : 0u;
    unsigned pos = offset + v - eq;             // exclusive prefix of equals before my chunk

    // ---- write out = x * mask ----
    float4* op = reinterpret_cast<float4*>(out + base);
#pragma unroll
    for (int q = 0; q < EPT / 4; ++q) {
        float vals[4];
#pragma unroll
        for (int jj = 0; jj < 4; ++jj) {
            int j = 4 * q + jj;
            bool sel;
            if (key[j] > thr)       sel = true;
            else if (key[j] == thr) { sel = (pos < Kr); ++pos; }
            else                    sel = false;
            vals[jj] = sel ? xv[j] : 0.0f;
        }
        float4 o4; o4.x = vals[0]; o4.y = vals[1]; o4.z = vals[2]; o4.w = vals[3];
        op[q] = o4;
    }
}

__global__ void skw_zero(float* p) { *p = 0.0f; }

// Deterministic fixed-order mean of rowH -> out scalar.
__global__ void skw_reduce(const float* __restrict__ rowH, float* __restrict__ outp, int B)
{
    __shared__ float red[256];
    int t = threadIdx.x;
    float s = 0.f;
    for (int i = t; i < B; i += 256) s += rowH[i];
    red[t] = s; __syncthreads();
    for (int st = 128; st > 0; st >>= 1) { if (t < st) red[t] += red[t + st]; __syncthreads(); }
    if (t == 0) *outp = red[0] / (float)B;
}

extern "C" void kernel_launch(void* const* d_in, const int* in_sizes, int n_in,
                              void* d_out, int out_size, void* d_ws, size_t ws_size,
                              hipStream_t stream)
{
    const float* x = (const float*)d_in[0];
    const float* g = (const float*)d_in[1];
    float* out = (float*)d_out;
    const int BN = in_sizes[0];
    const int B  = BN / NN;
    float* entp = out + (size_t)BN;

    if (ws_size >= (size_t)B * sizeof(float)) {
        float* rowH = (float*)d_ws;
        skw_main<true><<<B, TPB, 0, stream>>>(x, g, out, rowH, nullptr, 0.f);
        skw_reduce<<<1, 256, 0, stream>>>(rowH, entp, B);
    } else {
        skw_zero<<<1, 1, 0, stream>>>(entp);
        skw_main<false><<<B, TPB, 0, stream>>>(x, g, out, nullptr, entp, 1.0f / (float)B);
    }
}